// Round 1
// baseline (164.832 us; speedup 1.0000x reference)
//
#include <hip/hip_runtime.h>
#include <math.h>

#define NI 256
#define NO 256
#define BATCH 1024

// out[b,o] = C_o + (sum_i xs[b,i] - sum_o C_o) / NO
// where C_o = sum_j softplus(param[o*NI + j]).
// Derivation: M = lhs lhs^T = [[NO*I, B],[B^T, 2I]] with 1^T B = 0, so the
// sum of the input-node multipliers is (1/NO) * (sum_i xs[b,i] - total_c),
// and the +/-1 equal-edge terms cancel in the per-output sum.

__device__ __forceinline__ float softplus_f(float x) {
    // log(1+exp(x)), numerically stable: max(x,0) + log1p(exp(-|x|))
    return fmaxf(x, 0.0f) + log1pf(expf(-fabsf(x)));
}

__device__ __forceinline__ float block_reduce_256(float v, float* lds) {
    // 256 threads = 4 waves of 64
    #pragma unroll
    for (int off = 32; off > 0; off >>= 1)
        v += __shfl_down(v, off, 64);
    const int lane = threadIdx.x & 63;
    const int wave = threadIdx.x >> 6;
    if (lane == 0) lds[wave] = v;
    __syncthreads();
    float t = 0.0f;
    if (threadIdx.x < 4) t = lds[threadIdx.x];
    t += __shfl_down(t, 2, 64);
    t += __shfl_down(t, 1, 64);
    if (threadIdx.x == 0) lds[0] = t;
    __syncthreads();
    return lds[0];
}

// grid = NO + BATCH blocks of 256 threads.
// blocks [0, NO):   ws[o]      = C_o = sum_j softplus(param[o*NI+j])
// blocks [NO, ...): ws[NO + b] = Sx_b = sum_i xs[b*NI+i]
__global__ __launch_bounds__(256) void reduce_kernel(const float* __restrict__ xs,
                                                     const float* __restrict__ param,
                                                     float* __restrict__ ws) {
    __shared__ float lds[4];
    const int bid = blockIdx.x;
    const int tid = threadIdx.x;
    float v;
    if (bid < NO) {
        v = softplus_f(param[bid * NI + tid]);
    } else {
        v = xs[(bid - NO) * NI + tid];
    }
    const float s = block_reduce_256(v, lds);
    if (tid == 0) ws[bid] = s;
}

// grid = BATCH blocks of NO threads. Block b, thread o:
// out[b*NO + o] = C_o + (Sx_b - total) / NO
// total is recomputed per block by reducing the 256 C_o values (L2-resident).
__global__ __launch_bounds__(256) void out_kernel(const float* __restrict__ ws,
                                                  float* __restrict__ out) {
    __shared__ float lds[4];
    const int b = blockIdx.x;
    const int o = threadIdx.x;
    const float Co = ws[o];
    const float total = block_reduce_256(Co, lds);
    const float Sx = ws[NO + b];
    out[b * NO + o] = Co + (Sx - total) * (1.0f / (float)NO);
}

extern "C" void kernel_launch(void* const* d_in, const int* in_sizes, int n_in,
                              void* d_out, int out_size, void* d_ws, size_t ws_size,
                              hipStream_t stream) {
    const float* xs    = (const float*)d_in[0];   // [BATCH, NI]
    const float* param = (const float*)d_in[1];   // [NO*NI]
    // d_in[2] (lhs) is not needed: its structure is folded into the closed form.
    float* out = (float*)d_out;                   // [BATCH, NO]
    float* ws  = (float*)d_ws;                    // NO + BATCH floats

    reduce_kernel<<<NO + BATCH, 256, 0, stream>>>(xs, param, ws);
    out_kernel<<<BATCH, 256, 0, stream>>>(ws, out);
}